// Round 4
// baseline (85.804 us; speedup 1.0000x reference)
//
#include <hip/hip_runtime.h>

#define BB 4
#define NN 4096

typedef __attribute__((ext_vector_type(8))) short short8v;   // 8 bf16 = 4 VGPRs
typedef __attribute__((ext_vector_type(4))) short short4v;   // 4 bf16 = 2 VGPRs
typedef __attribute__((ext_vector_type(4))) float float4v;
typedef __attribute__((ext_vector_type(16))) float f32x16;   // 32x32 MFMA acc

__device__ __forceinline__ unsigned short f2bf_rn(float f) {
    unsigned u = __float_as_uint(f);
    u += 0x7FFFu + ((u >> 16) & 1u);          // round-to-nearest-even
    return (unsigned short)(u >> 16);
}

// ---------------------------------------------------------------------------
// Kernel 1: fused QKV projection, 512-thread blocks on 32-n tiles.
// Grid 128x4 = 512 blocks = 2 blocks/CU -> 4 waves/SIMD (vs 1 in the old
// 256-thread/64-n version): global-load + LDS-gather latencies now overlap.
// Wq pre-scaled by log2(e) so the attention loop uses raw exp2.
// Outputs:
//   Qt[b][n][8], Kt[b][n][8]  (contiguous 16B rows)
//   Vsw: V pre-swizzled into 32x32x16 MFMA A-fragment order: 1 KB chunk per
//   (b, ct in [0,2), ns = n/16): elem[l*8+j] = V[b][ct*32+(l&31)][ns*16+(l>>5)*8+j]
// ---------------------------------------------------------------------------
__global__ __launch_bounds__(512) void qkv_kernel(
    const float* __restrict__ x,
    const float* __restrict__ Wq, const float* __restrict__ Wk,
    const float* __restrict__ Wv,
    unsigned short* __restrict__ Qt, unsigned short* __restrict__ Kt,
    unsigned short* __restrict__ Vsw)
{
    __shared__ __align__(16) unsigned short xs[64][40];   // [c][n] bf16, 80B rows
    __shared__ __align__(16) unsigned short Ot[64][40];   // [c][n] V staging

    const int t    = threadIdx.x;
    const int w    = t >> 6;
    const int lane = t & 63;
    const int quad = lane >> 4;
    const int l15  = lane & 15;
    const int hi   = lane >> 5;
    const int l31  = lane & 31;
    const int b    = blockIdx.y;
    const int n0   = blockIdx.x * 32;

    const float4v zacc4 = {0.f, 0.f, 0.f, 0.f};

    // ---- stage x tile (fp32 -> bf16): thread -> (c = t>>3, 4 n)
    {
        int c = t >> 3, n4 = (t & 7) * 4;
        float4 xv = *(const float4*)&x[(size_t)(b * 64 + c) * NN + n0 + n4];
        short4v pk;
        pk[0] = (short)f2bf_rn(xv.x); pk[1] = (short)f2bf_rn(xv.y);
        pk[2] = (short)f2bf_rn(xv.z); pk[3] = (short)f2bf_rn(xv.w);
        *(short4v*)&xs[c][n4] = pk;
    }
    __syncthreads();

    // ---- tile list: wave w does (ot=w>>1, nt=w&1); waves 0,1 also do (4, w)
    #pragma unroll
    for (int ti = 0; ti < 2; ++ti) {
        int ot, nt;
        if (ti == 0) { ot = w >> 1; nt = w & 1; }
        else         { if (w >= 2) break; ot = 4; nt = w; }

        // B-fragment: B[k=c][o=l15] (Wq rows scaled by log2 e)
        int o = ot * 16 + l15;
        const float* base = (o < 8)  ? (Wq + o * 64)
                           : (o < 16) ? (Wk + (o - 8) * 64)
                                      : (Wv + (o - 16) * 64);
        const float scale = (o < 8) ? 1.4426950408889634f : 1.0f;
        short8v bw0, bw1;
        {
            float4 u0 = *(const float4*)&base[quad * 8];
            float4 u1 = *(const float4*)&base[quad * 8 + 4];
            bw0[0] = (short)f2bf_rn(u0.x * scale); bw0[1] = (short)f2bf_rn(u0.y * scale);
            bw0[2] = (short)f2bf_rn(u0.z * scale); bw0[3] = (short)f2bf_rn(u0.w * scale);
            bw0[4] = (short)f2bf_rn(u1.x * scale); bw0[5] = (short)f2bf_rn(u1.y * scale);
            bw0[6] = (short)f2bf_rn(u1.z * scale); bw0[7] = (short)f2bf_rn(u1.w * scale);
            float4 u2 = *(const float4*)&base[32 + quad * 8];
            float4 u3 = *(const float4*)&base[32 + quad * 8 + 4];
            bw1[0] = (short)f2bf_rn(u2.x * scale); bw1[1] = (short)f2bf_rn(u2.y * scale);
            bw1[2] = (short)f2bf_rn(u2.z * scale); bw1[3] = (short)f2bf_rn(u2.w * scale);
            bw1[4] = (short)f2bf_rn(u3.x * scale); bw1[5] = (short)f2bf_rn(u3.y * scale);
            bw1[6] = (short)f2bf_rn(u3.z * scale); bw1[7] = (short)f2bf_rn(u3.w * scale);
        }

        // A-fragment: A[m=n][k=c] gathered from xs
        short8v a0, a1;
        {
            unsigned short* p0 = (unsigned short*)&a0;
            unsigned short* p1 = (unsigned short*)&a1;
            const int nn = nt * 16 + l15;
            #pragma unroll
            for (int j = 0; j < 8; ++j) {
                p0[j] = xs[quad * 8 + j][nn];
                p1[j] = xs[32 + quad * 8 + j][nn];
            }
        }

        float4v d = __builtin_amdgcn_mfma_f32_16x16x32_bf16(a0, bw0, zacc4, 0, 0, 0);
        d = __builtin_amdgcn_mfma_f32_16x16x32_bf16(a1, bw1, d, 0, 0, 0);

        if (ot == 0) {
            #pragma unroll
            for (int r = 0; r < 4; ++r) {
                unsigned short v = f2bf_rn(d[r]);
                size_t n = (size_t)(n0 + nt * 16 + quad * 4 + r);
                if (l15 < 8) Qt[((size_t)b * NN + n) * 8 + l15] = v;
                else         Kt[((size_t)b * NN + n) * 8 + (l15 - 8)] = v;
            }
        } else {
            short4v pk;
            #pragma unroll
            for (int r = 0; r < 4; ++r) pk[r] = (short)f2bf_rn(d[r]);
            *(short4v*)&Ot[(ot - 1) * 16 + l15][nt * 16 + quad * 4] = pk;
        }
    }
    __syncthreads();

    // ---- swizzled V writer: 4 chunks of 1 KB (waves 0-3), fully coalesced
    if (w < 4) {
        int ct = w >> 1, nsl = w & 1;
        short8v d = *(const short8v*)&Ot[ct * 32 + l31][nsl * 16 + hi * 8];
        size_t ns = (size_t)blockIdx.x * 2 + nsl;
        unsigned short* cb = Vsw + (((size_t)b * 2 + ct) * 256 + ns) * 512;
        *(short8v*)(cb + lane * 8) = d;
    }
}

// ---------------------------------------------------------------------------
// Kernel 2: streaming attention, 32x32x16 MFMA, fully in-register softmax.
// vs r2: the 16 v_add_f32 column-sum accumulations per iter (plus the final
// shuffle) are replaced by 2 extra MFMAs with an all-ones A-fragment into a
// separate accumulator (accL += ones * P) -> column sums land on the mostly
// idle matrix pipe; VALU per iter drops to exp/pack/permlane only.
// ---------------------------------------------------------------------------
__global__ __launch_bounds__(512, 4) void attn_kernel(
    const unsigned short* __restrict__ Qt,
    const unsigned short* __restrict__ Kt,
    const unsigned short* __restrict__ Vsw,
    const float* __restrict__ x, const float* __restrict__ gamma,
    float* __restrict__ out)
{
    __shared__ __align__(16) float Ored[4][64][36];   // 36.9 KB
    __shared__ __align__(16) float Lred[8][32];
    __shared__ __align__(16) float Lf[32];

    const int t    = threadIdx.x;
    const int w    = t >> 6;
    const int lane = t & 63;
    const int hi   = lane >> 5;
    const int l31  = lane & 31;
    const int b    = blockIdx.y;
    const int m0   = blockIdx.x * 32;

    const short8v zfrag = {0, 0, 0, 0, 0, 0, 0, 0};
    const short8v aones = {16256, 16256, 16256, 16256,
                           16256, 16256, 16256, 16256};   // bf16 1.0 x8
    const f32x16 zero16 = {0.f, 0.f, 0.f, 0.f, 0.f, 0.f, 0.f, 0.f,
                           0.f, 0.f, 0.f, 0.f, 0.f, 0.f, 0.f, 0.f};

    // K-side (query-column) B fragment: k=c=(hi*8+j); only c<8 real -> lo half
    short8v bk = zfrag;
    if (!hi) bk = *(const short8v*)(Kt + ((size_t)b * NN + m0 + l31) * 8);

    f32x16 acc0 = zero16, acc1 = zero16, accL = zero16;

    const unsigned short* qp  = Qt + ((size_t)b * NN + w * 512) * 8;
    const unsigned short* v0p = Vsw + ((size_t)b * 2 * 256 + w * 32) * 512 + lane * 8;
    const unsigned short* v1p = v0p + 256 * 512;

    // ---- prefetch Q for iter 0
    short8v aqn = zfrag;
    if (!hi) aqn = *(const short8v*)(qp + (size_t)l31 * 8);

    for (int it = 0; it < 16; ++it) {
        // V loads for THIS iter: issued now, consumed by PV after QK+exp+pack
        short8v a00 = *(const short8v*)(v0p + it * 1024);
        short8v a01 = *(const short8v*)(v0p + it * 1024 + 512);
        short8v a10 = *(const short8v*)(v1p + it * 1024);
        short8v a11 = *(const short8v*)(v1p + it * 1024 + 512);

        short8v aq = aqn;

        // ---- scores: 32n x 32m in one MFMA (K=16, 8 real c); pre-scaled log2 e
        f32x16 s = __builtin_amdgcn_mfma_f32_32x32x16_bf16(aq, bk, zero16, 0, 0, 0);

        const int itn = (it + 1) & 15;
        if (!hi) aqn = *(const short8v*)(qp + (size_t)(itn * 32 + l31) * 8);

        // ---- fused exp2 + bf16 pack (rows 2t,2t+1 per word); no scalar sums
        unsigned xw[8];
        #pragma unroll
        for (int j = 0; j < 8; ++j) {
            float e0 = __builtin_amdgcn_exp2f(s[2 * j]);
            float e1 = __builtin_amdgcn_exp2f(s[2 * j + 1]);
            asm("v_cvt_pk_bf16_f32 %0, %1, %2" : "=v"(xw[j]) : "v"(e0), "v"(e1));
        }

        // ---- D->B transpose entirely in registers (halves exchange)
        asm("v_permlane32_swap_b32 %0, %1" : "+v"(xw[2]), "+v"(xw[0]));
        asm("v_permlane32_swap_b32 %0, %1" : "+v"(xw[3]), "+v"(xw[1]));
        asm("v_permlane32_swap_b32 %0, %1" : "+v"(xw[6]), "+v"(xw[4]));
        asm("v_permlane32_swap_b32 %0, %1" : "+v"(xw[7]), "+v"(xw[5]));

        union { unsigned u[4]; short8v v; } bp0, bp1;
        bp0.u[0] = xw[0]; bp0.u[1] = xw[1]; bp0.u[2] = xw[2]; bp0.u[3] = xw[3];
        bp1.u[0] = xw[4]; bp1.u[1] = xw[5]; bp1.u[2] = xw[6]; bp1.u[3] = xw[7];

        // ---- PV: O[c][m] += V[c][n] * P[n][m]; L[m] += sum_n P[n][m]
        __builtin_amdgcn_s_setprio(1);
        acc0 = __builtin_amdgcn_mfma_f32_32x32x16_bf16(a00, bp0.v, acc0, 0, 0, 0);
        acc0 = __builtin_amdgcn_mfma_f32_32x32x16_bf16(a01, bp1.v, acc0, 0, 0, 0);
        acc1 = __builtin_amdgcn_mfma_f32_32x32x16_bf16(a10, bp0.v, acc1, 0, 0, 0);
        acc1 = __builtin_amdgcn_mfma_f32_32x32x16_bf16(a11, bp1.v, acc1, 0, 0, 0);
        accL = __builtin_amdgcn_mfma_f32_32x32x16_bf16(aones, bp0.v, accL, 0, 0, 0);
        accL = __builtin_amdgcn_mfma_f32_32x32x16_bf16(aones, bp1.v, accL, 0, 0, 0);
        __builtin_amdgcn_s_setprio(0);
    }

    // ---- accL[0] = this wave's column-partial L for col m0+l31 (all rows equal)
    if (lane < 32) Lred[w][l31] = accL[0];

    // ---- O reduction: waves 0-3 write their partial, waves 4-7 RMW-add
    if (w < 4) {
        #pragma unroll
        for (int r = 0; r < 16; ++r) {
            int c = (r & 3) + 8 * (r >> 2) + 4 * hi;
            Ored[w][c][l31]      = acc0[r];
            Ored[w][c + 32][l31] = acc1[r];
        }
    }
    __syncthreads();
    if (w >= 4) {
        #pragma unroll
        for (int r = 0; r < 16; ++r) {
            int c = (r & 3) + 8 * (r >> 2) + 4 * hi;
            Ored[w - 4][c][l31]      += acc0[r];
            Ored[w - 4][c + 32][l31] += acc1[r];
        }
    }
    if (t < 32) {
        float sum = Lred[0][t] + Lred[1][t] + Lred[2][t] + Lred[3][t]
                  + Lred[4][t] + Lred[5][t] + Lred[6][t] + Lred[7][t];
        Lf[t] = 1.f / sum;
    }
    __syncthreads();

    // ---- vectorized epilogue: thread -> (c = t>>3, 4 consecutive m)
    {
        const float gv = gamma[0];
        int c = t >> 3, m4 = (t & 7) * 4;
        float4 o = {0.f, 0.f, 0.f, 0.f};
        #pragma unroll
        for (int k2 = 0; k2 < 4; ++k2) {
            float4 v = *(const float4*)&Ored[k2][c][m4];
            o.x += v.x; o.y += v.y; o.z += v.z; o.w += v.w;
        }
        float4 lf = *(const float4*)&Lf[m4];
        size_t gbase = ((size_t)b * 64 + c) * NN + m0 + m4;
        float4 xv = *(const float4*)&x[gbase];
        float4 r;
        r.x = gv * o.x * lf.x + xv.x;
        r.y = gv * o.y * lf.y + xv.y;
        r.z = gv * o.z * lf.z + xv.z;
        r.w = gv * o.w * lf.w + xv.w;
        *(float4*)&out[gbase] = r;
    }
}

extern "C" void kernel_launch(void* const* d_in, const int* in_sizes, int n_in,
                              void* d_out, int out_size, void* d_ws, size_t ws_size,
                              hipStream_t stream) {
    const float* x     = (const float*)d_in[0];
    const float* Wq    = (const float*)d_in[1];
    const float* Wk    = (const float*)d_in[2];
    const float* Wv    = (const float*)d_in[3];
    const float* gamma = (const float*)d_in[4];
    float* out = (float*)d_out;

    unsigned short* ws = (unsigned short*)d_ws;
    unsigned short* Qt  = ws;                        // [B][N][8]  bf16, 256 KB
    unsigned short* Kt  = Qt + (size_t)BB * NN * 8;  // [B][N][8]  bf16, 256 KB
    unsigned short* Vsw = Kt + (size_t)BB * NN * 8;  // [B][2][256][512] bf16, 2 MB

    qkv_kernel<<<dim3(NN / 32, BB), 512, 0, stream>>>(x, Wq, Wk, Wv, Qt, Kt, Vsw);
    attn_kernel<<<dim3(NN / 32, BB), 512, 0, stream>>>(Qt, Kt, Vsw, x, gamma, out);
}

// Round 5
// 84.201 us; speedup vs baseline: 1.0190x; 1.0190x over previous
//
#include <hip/hip_runtime.h>

#define BB 4
#define NN 4096

typedef __attribute__((ext_vector_type(8))) short short8v;   // 8 bf16 = 4 VGPRs
typedef __attribute__((ext_vector_type(4))) short short4v;   // 4 bf16 = 2 VGPRs
typedef __attribute__((ext_vector_type(4))) float float4v;
typedef __attribute__((ext_vector_type(16))) float f32x16;   // 32x32 MFMA acc

__device__ __forceinline__ unsigned short f2bf_rn(float f) {
    unsigned u = __float_as_uint(f);
    u += 0x7FFFu + ((u >> 16) & 1u);          // round-to-nearest-even
    return (unsigned short)(u >> 16);
}

// ---------------------------------------------------------------------------
// Kernel 1: fused QKV projection, 512-thread blocks on 32-n tiles (as r4).
// Wq pre-scaled by log2(e) so the attention loop uses raw exp2.
// Outputs:
//   Qt[b][n][8], Kt[b][n][8]  (contiguous 16B rows)
//   Vsw: V pre-swizzled into 32x32x16 MFMA A-fragment order: 1 KB chunk per
//   (b, ct in [0,2), ns = n/16): elem[l*8+j] = V[b][ct*32+(l&31)][ns*16+(l>>5)*8+j]
// ---------------------------------------------------------------------------
__global__ __launch_bounds__(512) void qkv_kernel(
    const float* __restrict__ x,
    const float* __restrict__ Wq, const float* __restrict__ Wk,
    const float* __restrict__ Wv,
    unsigned short* __restrict__ Qt, unsigned short* __restrict__ Kt,
    unsigned short* __restrict__ Vsw)
{
    __shared__ __align__(16) unsigned short xs[64][40];   // [c][n] bf16, 80B rows
    __shared__ __align__(16) unsigned short Ot[64][40];   // [c][n] V staging

    const int t    = threadIdx.x;
    const int w    = t >> 6;
    const int lane = t & 63;
    const int quad = lane >> 4;
    const int l15  = lane & 15;
    const int hi   = lane >> 5;
    const int l31  = lane & 31;
    const int b    = blockIdx.y;
    const int n0   = blockIdx.x * 32;

    const float4v zacc4 = {0.f, 0.f, 0.f, 0.f};

    // ---- stage x tile (fp32 -> bf16): thread -> (c = t>>3, 4 n)
    {
        int c = t >> 3, n4 = (t & 7) * 4;
        float4 xv = *(const float4*)&x[(size_t)(b * 64 + c) * NN + n0 + n4];
        short4v pk;
        pk[0] = (short)f2bf_rn(xv.x); pk[1] = (short)f2bf_rn(xv.y);
        pk[2] = (short)f2bf_rn(xv.z); pk[3] = (short)f2bf_rn(xv.w);
        *(short4v*)&xs[c][n4] = pk;
    }
    __syncthreads();

    // ---- tile list: wave w does (ot=w>>1, nt=w&1); waves 0,1 also do (4, w)
    #pragma unroll
    for (int ti = 0; ti < 2; ++ti) {
        int ot, nt;
        if (ti == 0) { ot = w >> 1; nt = w & 1; }
        else         { if (w >= 2) break; ot = 4; nt = w; }

        // B-fragment: B[k=c][o=l15] (Wq rows scaled by log2 e)
        int o = ot * 16 + l15;
        const float* base = (o < 8)  ? (Wq + o * 64)
                           : (o < 16) ? (Wk + (o - 8) * 64)
                                      : (Wv + (o - 16) * 64);
        const float scale = (o < 8) ? 1.4426950408889634f : 1.0f;
        short8v bw0, bw1;
        {
            float4 u0 = *(const float4*)&base[quad * 8];
            float4 u1 = *(const float4*)&base[quad * 8 + 4];
            bw0[0] = (short)f2bf_rn(u0.x * scale); bw0[1] = (short)f2bf_rn(u0.y * scale);
            bw0[2] = (short)f2bf_rn(u0.z * scale); bw0[3] = (short)f2bf_rn(u0.w * scale);
            bw0[4] = (short)f2bf_rn(u1.x * scale); bw0[5] = (short)f2bf_rn(u1.y * scale);
            bw0[6] = (short)f2bf_rn(u1.z * scale); bw0[7] = (short)f2bf_rn(u1.w * scale);
            float4 u2 = *(const float4*)&base[32 + quad * 8];
            float4 u3 = *(const float4*)&base[32 + quad * 8 + 4];
            bw1[0] = (short)f2bf_rn(u2.x * scale); bw1[1] = (short)f2bf_rn(u2.y * scale);
            bw1[2] = (short)f2bf_rn(u2.z * scale); bw1[3] = (short)f2bf_rn(u2.w * scale);
            bw1[4] = (short)f2bf_rn(u3.x * scale); bw1[5] = (short)f2bf_rn(u3.y * scale);
            bw1[6] = (short)f2bf_rn(u3.z * scale); bw1[7] = (short)f2bf_rn(u3.w * scale);
        }

        // A-fragment: A[m=n][k=c] gathered from xs
        short8v a0, a1;
        {
            unsigned short* p0 = (unsigned short*)&a0;
            unsigned short* p1 = (unsigned short*)&a1;
            const int nn = nt * 16 + l15;
            #pragma unroll
            for (int j = 0; j < 8; ++j) {
                p0[j] = xs[quad * 8 + j][nn];
                p1[j] = xs[32 + quad * 8 + j][nn];
            }
        }

        float4v d = __builtin_amdgcn_mfma_f32_16x16x32_bf16(a0, bw0, zacc4, 0, 0, 0);
        d = __builtin_amdgcn_mfma_f32_16x16x32_bf16(a1, bw1, d, 0, 0, 0);

        if (ot == 0) {
            #pragma unroll
            for (int r = 0; r < 4; ++r) {
                unsigned short v = f2bf_rn(d[r]);
                size_t n = (size_t)(n0 + nt * 16 + quad * 4 + r);
                if (l15 < 8) Qt[((size_t)b * NN + n) * 8 + l15] = v;
                else         Kt[((size_t)b * NN + n) * 8 + (l15 - 8)] = v;
            }
        } else {
            short4v pk;
            #pragma unroll
            for (int r = 0; r < 4; ++r) pk[r] = (short)f2bf_rn(d[r]);
            *(short4v*)&Ot[(ot - 1) * 16 + l15][nt * 16 + quad * 4] = pk;
        }
    }
    __syncthreads();

    // ---- swizzled V writer: 4 chunks of 1 KB (waves 0-3), fully coalesced
    if (w < 4) {
        int ct = w >> 1, nsl = w & 1;
        short8v d = *(const short8v*)&Ot[ct * 32 + l31][nsl * 16 + hi * 8];
        size_t ns = (size_t)blockIdx.x * 2 + nsl;
        unsigned short* cb = Vsw + (((size_t)b * 2 + ct) * 256 + ns) * 512;
        *(short8v*)(cb + lane * 8) = d;
    }
}

// ---------------------------------------------------------------------------
// Kernel 2: streaming attention, m-tile 64 (two 32-wide m-tiles per block,
// sharing the SAME V fragments) -> per-batch V re-read count halves vs r4:
// 256 blocks x 512 KB = 134 MB of L2 V traffic (was 268 MB). Wave w owns
// n in [w*512,(w+1)*512), 16 iters of 32 n; per iter: 2 QK MFMA, 2x softmax
// pack/transpose (in-register), 8 PV MFMA, 4 L MFMA. launch_bounds (512,2):
// 1 block/CU, VGPR cap 256 (est live ~195).
// ---------------------------------------------------------------------------
__global__ __launch_bounds__(512, 2) void attn_kernel(
    const unsigned short* __restrict__ Qt,
    const unsigned short* __restrict__ Kt,
    const unsigned short* __restrict__ Vsw,
    const float* __restrict__ x, const float* __restrict__ gamma,
    float* __restrict__ out)
{
    __shared__ __align__(16) float Ored[4][64][68];   // 69.6 KB
    __shared__ __align__(16) float Lred[8][2][32];
    __shared__ __align__(16) float Lf[64];

    const int t    = threadIdx.x;
    const int w    = t >> 6;
    const int lane = t & 63;
    const int hi   = lane >> 5;
    const int l31  = lane & 31;
    const int b    = blockIdx.y;
    const int m0   = blockIdx.x * 64;

    const short8v zfrag = {0, 0, 0, 0, 0, 0, 0, 0};
    const short8v aones = {16256, 16256, 16256, 16256,
                           16256, 16256, 16256, 16256};   // bf16 1.0 x8
    const f32x16 zero16 = {0.f, 0.f, 0.f, 0.f, 0.f, 0.f, 0.f, 0.f,
                           0.f, 0.f, 0.f, 0.f, 0.f, 0.f, 0.f, 0.f};

    // K-side B fragments for the two m-tiles: k=c=(hi*8+j); c<8 real -> lo half
    short8v bk0 = zfrag, bk1 = zfrag;
    if (!hi) {
        bk0 = *(const short8v*)(Kt + ((size_t)b * NN + m0 + l31) * 8);
        bk1 = *(const short8v*)(Kt + ((size_t)b * NN + m0 + 32 + l31) * 8);
    }

    // acc[A=c0..31 / B=c32..63][m-tile 0/1]
    f32x16 accA0 = zero16, accA1 = zero16, accB0 = zero16, accB1 = zero16;
    f32x16 accL0 = zero16, accL1 = zero16;

    const unsigned short* qp  = Qt + ((size_t)b * NN + w * 512) * 8;
    const unsigned short* v0p = Vsw + ((size_t)b * 2 * 256 + w * 32) * 512 + lane * 8;
    const unsigned short* v1p = v0p + 256 * 512;

    // ---- prefetch Q for iter 0
    short8v aqn = zfrag;
    if (!hi) aqn = *(const short8v*)(qp + (size_t)l31 * 8);

    for (int it = 0; it < 16; ++it) {
        // V loads for THIS iter (shared by both m-tiles)
        short8v a00 = *(const short8v*)(v0p + it * 1024);
        short8v a01 = *(const short8v*)(v0p + it * 1024 + 512);
        short8v a10 = *(const short8v*)(v1p + it * 1024);
        short8v a11 = *(const short8v*)(v1p + it * 1024 + 512);

        short8v aq = aqn;

        // ---- scores for both m-tiles (K=16, 8 real c); pre-scaled by log2 e
        f32x16 s0 = __builtin_amdgcn_mfma_f32_32x32x16_bf16(aq, bk0, zero16, 0, 0, 0);
        f32x16 s1 = __builtin_amdgcn_mfma_f32_32x32x16_bf16(aq, bk1, zero16, 0, 0, 0);

        const int itn = (it + 1) & 15;
        if (!hi) aqn = *(const short8v*)(qp + (size_t)(itn * 32 + l31) * 8);

        // ---- fused exp2 + bf16 pack, then in-register D->B transpose
        unsigned xw0[8], xw1[8];
        #pragma unroll
        for (int j = 0; j < 8; ++j) {
            float e0 = __builtin_amdgcn_exp2f(s0[2 * j]);
            float e1 = __builtin_amdgcn_exp2f(s0[2 * j + 1]);
            asm("v_cvt_pk_bf16_f32 %0, %1, %2" : "=v"(xw0[j]) : "v"(e0), "v"(e1));
        }
        #pragma unroll
        for (int j = 0; j < 8; ++j) {
            float e0 = __builtin_amdgcn_exp2f(s1[2 * j]);
            float e1 = __builtin_amdgcn_exp2f(s1[2 * j + 1]);
            asm("v_cvt_pk_bf16_f32 %0, %1, %2" : "=v"(xw1[j]) : "v"(e0), "v"(e1));
        }
        asm("v_permlane32_swap_b32 %0, %1" : "+v"(xw0[2]), "+v"(xw0[0]));
        asm("v_permlane32_swap_b32 %0, %1" : "+v"(xw0[3]), "+v"(xw0[1]));
        asm("v_permlane32_swap_b32 %0, %1" : "+v"(xw0[6]), "+v"(xw0[4]));
        asm("v_permlane32_swap_b32 %0, %1" : "+v"(xw0[7]), "+v"(xw0[5]));
        asm("v_permlane32_swap_b32 %0, %1" : "+v"(xw1[2]), "+v"(xw1[0]));
        asm("v_permlane32_swap_b32 %0, %1" : "+v"(xw1[3]), "+v"(xw1[1]));
        asm("v_permlane32_swap_b32 %0, %1" : "+v"(xw1[6]), "+v"(xw1[4]));
        asm("v_permlane32_swap_b32 %0, %1" : "+v"(xw1[7]), "+v"(xw1[5]));

        union { unsigned u[4]; short8v v; } bp00, bp01, bp10, bp11;
        bp00.u[0] = xw0[0]; bp00.u[1] = xw0[1]; bp00.u[2] = xw0[2]; bp00.u[3] = xw0[3];
        bp01.u[0] = xw0[4]; bp01.u[1] = xw0[5]; bp01.u[2] = xw0[6]; bp01.u[3] = xw0[7];
        bp10.u[0] = xw1[0]; bp10.u[1] = xw1[1]; bp10.u[2] = xw1[2]; bp10.u[3] = xw1[3];
        bp11.u[0] = xw1[4]; bp11.u[1] = xw1[5]; bp11.u[2] = xw1[6]; bp11.u[3] = xw1[7];

        // ---- PV + L: V fragments reused across both m-tiles
        __builtin_amdgcn_s_setprio(1);
        accA0 = __builtin_amdgcn_mfma_f32_32x32x16_bf16(a00, bp00.v, accA0, 0, 0, 0);
        accA0 = __builtin_amdgcn_mfma_f32_32x32x16_bf16(a01, bp01.v, accA0, 0, 0, 0);
        accB0 = __builtin_amdgcn_mfma_f32_32x32x16_bf16(a10, bp00.v, accB0, 0, 0, 0);
        accB0 = __builtin_amdgcn_mfma_f32_32x32x16_bf16(a11, bp01.v, accB0, 0, 0, 0);
        accA1 = __builtin_amdgcn_mfma_f32_32x32x16_bf16(a00, bp10.v, accA1, 0, 0, 0);
        accA1 = __builtin_amdgcn_mfma_f32_32x32x16_bf16(a01, bp11.v, accA1, 0, 0, 0);
        accB1 = __builtin_amdgcn_mfma_f32_32x32x16_bf16(a10, bp10.v, accB1, 0, 0, 0);
        accB1 = __builtin_amdgcn_mfma_f32_32x32x16_bf16(a11, bp11.v, accB1, 0, 0, 0);
        accL0 = __builtin_amdgcn_mfma_f32_32x32x16_bf16(aones, bp00.v, accL0, 0, 0, 0);
        accL0 = __builtin_amdgcn_mfma_f32_32x32x16_bf16(aones, bp01.v, accL0, 0, 0, 0);
        accL1 = __builtin_amdgcn_mfma_f32_32x32x16_bf16(aones, bp10.v, accL1, 0, 0, 0);
        accL1 = __builtin_amdgcn_mfma_f32_32x32x16_bf16(aones, bp11.v, accL1, 0, 0, 0);
        __builtin_amdgcn_s_setprio(0);
    }

    // ---- wave-partial column sums (all accL regs equal; read reg 0)
    if (lane < 32) {
        Lred[w][0][l31] = accL0[0];
        Lred[w][1][l31] = accL1[0];
    }

    // ---- O reduction: waves 0-3 write partials, waves 4-7 RMW-add
    if (w < 4) {
        #pragma unroll
        for (int r = 0; r < 16; ++r) {
            int c = (r & 3) + 8 * (r >> 2) + 4 * hi;
            Ored[w][c][l31]           = accA0[r];
            Ored[w][c][32 + l31]      = accA1[r];
            Ored[w][c + 32][l31]      = accB0[r];
            Ored[w][c + 32][32 + l31] = accB1[r];
        }
    }
    __syncthreads();
    if (w >= 4) {
        #pragma unroll
        for (int r = 0; r < 16; ++r) {
            int c = (r & 3) + 8 * (r >> 2) + 4 * hi;
            Ored[w - 4][c][l31]           += accA0[r];
            Ored[w - 4][c][32 + l31]      += accA1[r];
            Ored[w - 4][c + 32][l31]      += accB0[r];
            Ored[w - 4][c + 32][32 + l31] += accB1[r];
        }
    }
    if (t < 64) {
        int mt = t >> 5, m = t & 31;
        float sum = Lred[0][mt][m] + Lred[1][mt][m] + Lred[2][mt][m] + Lred[3][mt][m]
                  + Lred[4][mt][m] + Lred[5][mt][m] + Lred[6][mt][m] + Lred[7][mt][m];
        Lf[t] = 1.f / sum;
    }
    __syncthreads();

    // ---- epilogue: thread -> (c = t>>3, 8 consecutive m as 2x float4)
    {
        const float gv = gamma[0];
        int c = t >> 3, m8 = (t & 7) * 8;
        #pragma unroll
        for (int h = 0; h < 2; ++h) {
            int m4 = m8 + h * 4;
            float4 o = {0.f, 0.f, 0.f, 0.f};
            #pragma unroll
            for (int k2 = 0; k2 < 4; ++k2) {
                float4 v = *(const float4*)&Ored[k2][c][m4];
                o.x += v.x; o.y += v.y; o.z += v.z; o.w += v.w;
            }
            float4 lf = *(const float4*)&Lf[m4];
            size_t gbase = ((size_t)b * 64 + c) * NN + m0 + m4;
            float4 xv = *(const float4*)&x[gbase];
            float4 r;
            r.x = gv * o.x * lf.x + xv.x;
            r.y = gv * o.y * lf.y + xv.y;
            r.z = gv * o.z * lf.z + xv.z;
            r.w = gv * o.w * lf.w + xv.w;
            *(float4*)&out[gbase] = r;
        }
    }
}

extern "C" void kernel_launch(void* const* d_in, const int* in_sizes, int n_in,
                              void* d_out, int out_size, void* d_ws, size_t ws_size,
                              hipStream_t stream) {
    const float* x     = (const float*)d_in[0];
    const float* Wq    = (const float*)d_in[1];
    const float* Wk    = (const float*)d_in[2];
    const float* Wv    = (const float*)d_in[3];
    const float* gamma = (const float*)d_in[4];
    float* out = (float*)d_out;

    unsigned short* ws = (unsigned short*)d_ws;
    unsigned short* Qt  = ws;                        // [B][N][8]  bf16, 256 KB
    unsigned short* Kt  = Qt + (size_t)BB * NN * 8;  // [B][N][8]  bf16, 256 KB
    unsigned short* Vsw = Kt + (size_t)BB * NN * 8;  // [B][2][256][512] bf16, 2 MB

    qkv_kernel<<<dim3(NN / 32, BB), 512, 0, stream>>>(x, Wq, Wk, Wv, Qt, Kt, Vsw);
    attn_kernel<<<dim3(NN / 64, BB), 512, 0, stream>>>(Qt, Kt, Vsw, x, gamma, out);
}